// Round 3
// baseline (790.358 us; speedup 1.0000x reference)
//
#include <hip/hip_runtime.h>

// TemporalCrossAttention — MI355X (gfx950)
// B=8192, T=16, QD=320, HEADS=8, DH=64, INNER=512. ROWS = 131072.
// Mask == attend to {t-1, t}; rel tables only at idx 15,16.

typedef __attribute__((ext_vector_type(8))) short short8;
typedef __attribute__((ext_vector_type(4))) float floatx4;

#define NWQKV (8*192*320)   // 491520 elems
#define NWO   (320*512)     // 163840 elems
#define NRS   8192          // rowsets (= batch elems)

__device__ __forceinline__ unsigned short f2b(float x) {
  union { float f; unsigned int u; } t; t.f = x;
  unsigned int r = t.u + 0x7FFFu + ((t.u >> 16) & 1u);
  return (unsigned short)(r >> 16);
}

typedef const __attribute__((address_space(1))) unsigned int* gas_ptr;
typedef __attribute__((address_space(3))) unsigned int* las_ptr;

// 16B async global->LDS. LDS dest wave-uniform; HW scatters lane i to
// base + i*16. Global src per-lane.
__device__ __forceinline__ void gload16(const void* g, void* l) {
  __builtin_amdgcn_global_load_lds((gas_ptr)g, (las_ptr)l, 16, 0, 0);
}

// ---------------------------------------------------------------- prep ----
// wqkvT[h][c][k] (c: 0-63 q, 64-127 k, 128-191 v dims), woT[c][k] — bf16.
__global__ __launch_bounds__(256) void prep_kernel(
    const float* __restrict__ Wq, const float* __restrict__ Wk,
    const float* __restrict__ Wv, const float* __restrict__ Wo,
    unsigned short* __restrict__ wqkvT, unsigned short* __restrict__ woT) {
  int tid = blockIdx.x * 256 + threadIdx.x;
  if (tid < NWQKV) {
    int k = tid % 320;
    int c = (tid / 320) % 192;
    int h = tid / (320 * 192);
    int sel = c >> 6, d = c & 63;
    const float* W = (sel == 0) ? Wq : ((sel == 1) ? Wk : Wv);
    wqkvT[tid] = f2b(W[k * 512 + h * 64 + d]);
  } else {
    int i = tid - NWQKV;          // grid sized exactly: i < NWO
    int k = i & 511;
    int c = i >> 9;
    woT[i] = f2b(Wo[k * 320 + c]);
  }
}

// ------------------------------------------------- fused qkv + attention ----
// 256 threads (4 waves). Wave = 3 rowsets (48 rows). Per head: pass1 computes
// q,k (8 nf, acc 96 VGPR) -> in-register 2-key softmax -> pass2 computes v
// (4 nf) and the weighted combine. A fragments register-resident for all K.
// B double-buffered in LDS via global_load_lds, BK=64 phases.
__global__ __launch_bounds__(256, 2) void qkv_attn_kernel(
    const float* __restrict__ x, const float* __restrict__ relk,
    const float* __restrict__ relv, const unsigned short* __restrict__ wqkvT,
    unsigned short* __restrict__ attnout) {
  __shared__ short8 bq1[2][1024];   // pass1: 16 slots (8nf x 2ksub) x 64 lanes
  __shared__ short8 bq2[2][512];    // pass2:  8 slots (4nf x 2ksub) x 64 lanes
  const int tid = threadIdx.x;
  const int lane = tid & 63;
  const int w = tid >> 6;           // 0..3
  const int lr = lane & 15;
  const int g = lane >> 4;          // 0..3
  const int rs0 = blockIdx.x * 12 + w * 3;   // first global rowset of wave

  auto stage1 = [&](int h, int p, int cb) {   // q,k cols: c in [0,128)
    const unsigned short* wb = wqkvT + h * 61440;
#pragma unroll
    for (int i = 0; i < 4; i++) {
      int slot = w * 4 + i;
      int nf = slot & 7, ksub = slot >> 3;
      gload16(wb + (nf * 16 + lr) * 320 + p * 64 + ksub * 32 + g * 8,
              &bq1[cb][slot * 64]);
    }
  };
  auto stage2 = [&](int h, int p, int cb) {   // v cols: c in [128,192)
    const unsigned short* wb = wqkvT + h * 61440 + 40960;
#pragma unroll
    for (int i = 0; i < 2; i++) {
      int slot = w * 2 + i;
      int nf = slot & 3, ksub = slot >> 2;
      gload16(wb + (nf * 16 + lr) * 320 + p * 64 + ksub * 32 + g * 8,
              &bq2[cb][slot * 64]);
    }
  };

  stage1(0, 0, 0);    // in flight under the x/rel loads below

  float rk15v[4], rk16v[4], rv15v[4], rv16v[4];
#pragma unroll
  for (int f = 0; f < 4; f++) {
    int d = f * 16 + lr;
    rk15v[f] = relk[15 * 64 + d];
    rk16v[f] = relk[16 * 64 + d];
    rv15v[f] = relv[15 * 64 + d];
    rv16v[f] = relv[16 * 64 + d];
  }

  // A fragments: rowset rs (clamped), row = rsg*16 + lr, k = ks*32 + g*8
  short8 af[3][10];
#pragma unroll
  for (int rs = 0; rs < 3; rs++) {
    int rsg = rs0 + rs; if (rsg > NRS - 1) rsg = NRS - 1;
    const float* xrow = x + (size_t)(rsg * 16 + lr) * 320;
#pragma unroll
    for (int ks = 0; ks < 10; ks++) {
      const float4 u0 = *(const float4*)(xrow + ks * 32 + g * 8);
      const float4 u1 = *(const float4*)(xrow + ks * 32 + g * 8 + 4);
      short8 a;
      a[0] = (short)f2b(u0.x); a[1] = (short)f2b(u0.y);
      a[2] = (short)f2b(u0.z); a[3] = (short)f2b(u0.w);
      a[4] = (short)f2b(u1.x); a[5] = (short)f2b(u1.y);
      a[6] = (short)f2b(u1.z); a[7] = (short)f2b(u1.w);
      af[rs][ks] = a;
    }
  }

#pragma unroll 1
  for (int h = 0; h < 8; ++h) {
    // ---------------- pass 1: q,k ----------------
    floatx4 acc1[3][8];
#pragma unroll
    for (int rs = 0; rs < 3; rs++)
#pragma unroll
      for (int nf = 0; nf < 8; nf++) acc1[rs][nf] = (floatx4){0.f,0.f,0.f,0.f};

#pragma unroll
    for (int p = 0; p < 5; ++p) {
      const int cb = p & 1;
      __syncthreads();
      if (p < 4) stage1(h, p + 1, cb ^ 1);
      else       stage2(h, 0, 0);
#pragma unroll
      for (int ksub = 0; ksub < 2; ++ksub)
#pragma unroll
        for (int nf = 0; nf < 8; ++nf) {
          short8 b = bq1[cb][(ksub * 8 + nf) * 64 + lane];
#pragma unroll
          for (int rs = 0; rs < 3; rs++)
            acc1[rs][nf] = __builtin_amdgcn_mfma_f32_16x16x32_bf16(
                af[rs][p * 2 + ksub], b, acc1[rs][nf], 0, 0, 0);
        }
    }

    // ---------------- softmax (regs only; overlaps stage2 flight) ----------
    float a0[3][4], a1[3][4];
#pragma unroll
    for (int rs = 0; rs < 3; rs++) {
#pragma unroll
      for (int reg = 0; reg < 4; reg++) {
        float c0 = 0.f, c1 = 0.f;
#pragma unroll
        for (int f = 0; f < 4; f++) {
          float q  = acc1[rs][f][reg];
          float kk = acc1[rs][4 + f][reg];
          float kp = (reg > 0) ? acc1[rs][4 + f][reg - 1]
                               : __shfl(acc1[rs][4 + f][3], (lane - 16) & 63, 64);
          c0 += q * (kk + rk16v[f]);
          c1 += q * (kp + rk15v[f]);
        }
#pragma unroll
        for (int m = 1; m < 16; m <<= 1) {
          c0 += __shfl_xor(c0, m, 16);
          c1 += __shfl_xor(c1, m, 16);
        }
        float S0 = c0 * 0.125f, S1 = c1 * 0.125f;
        int t = g * 4 + reg;
        float mm = fmaxf(S0, S1);
        float e0 = __expf(S0 - mm), e1 = __expf(S1 - mm);
        float inv = 1.f / (e0 + e1);
        a0[rs][reg] = (t == 0) ? 1.f : e0 * inv;
        a1[rs][reg] = (t == 0) ? 0.f : e1 * inv;
      }
    }

    // ---------------- pass 2: v ----------------
    floatx4 accv[3][4];
#pragma unroll
    for (int rs = 0; rs < 3; rs++)
#pragma unroll
      for (int nf = 0; nf < 4; nf++) accv[rs][nf] = (floatx4){0.f,0.f,0.f,0.f};

#pragma unroll
    for (int p = 0; p < 5; ++p) {
      const int cb = p & 1;
      __syncthreads();
      if (p < 4)      stage2(h, p + 1, cb ^ 1);
      else if (h < 7) stage1(h + 1, 0, 0);
#pragma unroll
      for (int ksub = 0; ksub < 2; ++ksub)
#pragma unroll
        for (int nf = 0; nf < 4; ++nf) {
          short8 b = bq2[cb][(ksub * 4 + nf) * 64 + lane];
#pragma unroll
          for (int rs = 0; rs < 3; rs++)
            accv[rs][nf] = __builtin_amdgcn_mfma_f32_16x16x32_bf16(
                af[rs][p * 2 + ksub], b, accv[rs][nf], 0, 0, 0);
        }
    }

    // ---------------- combine + store (overlaps stage1(h+1) flight) -------
#pragma unroll
    for (int rs = 0; rs < 3; rs++) {
      const bool valid = (rs0 + rs) < NRS;
#pragma unroll
      for (int reg = 0; reg < 4; reg++) {
        int t = g * 4 + reg;
        size_t base = (size_t)((size_t)(rs0 + rs) * 16 + t) * 512 + h * 64 + lr;
#pragma unroll
        for (int f = 0; f < 4; f++) {
          float vv = accv[rs][f][reg];
          float vp = (reg > 0) ? accv[rs][f][reg - 1]
                               : __shfl(accv[rs][f][3], (lane - 16) & 63, 64);
          float o = a0[rs][reg] * (vv + rv16v[f]) + a1[rs][reg] * (vp + rv15v[f]);
          if (valid) attnout[base + f * 16] = f2b(o);
        }
      }
    }
  }
}

// ------------------------------------------------------- output projection ----
// out[131072,320] = attnout@Wo + bo. 512 threads, 8 waves = 4 M-groups x 2
// N-halves; wave tile 32 rows x 160 cols. A (attnout) register-resident
// (af[2][16]); B LDS double-buffered BK=64. Grid 1024 — exactly 4 rounds/CU.
__global__ __launch_bounds__(512, 2) void out_proj_kernel(
    const unsigned short* __restrict__ attnout,
    const unsigned short* __restrict__ woT,
    const float* __restrict__ bo, float* __restrict__ out) {
  __shared__ short8 sB[2][2560];    // 40 slots (20nf x 2ksub) x 64 lanes
  const int tid = threadIdx.x;
  const int lane = tid & 63;
  const int w = tid >> 6;           // 0..7
  const int lr = lane & 15;
  const int g = lane >> 4;
  const int mg = w >> 1, nh = w & 1;
  const int row0 = blockIdx.x * 128 + mg * 32;

  auto stage = [&](int p, int cb) {
#pragma unroll
    for (int i = 0; i < 5; i++) {
      int slot = w * 5 + i;
      int nf = slot % 20, ksub = slot / 20;
      gload16(woT + (nf * 16 + lr) * 512 + p * 64 + ksub * 32 + g * 8,
              &sB[cb][slot * 64]);
    }
  };

  stage(0, 0);    // in flight under the A loads

  short8 af[2][16];
#pragma unroll
  for (int rs = 0; rs < 2; rs++) {
    const unsigned short* ar = attnout + (size_t)(row0 + rs * 16 + lr) * 512;
#pragma unroll
    for (int ks = 0; ks < 16; ks++)
      af[rs][ks] = *(const short8*)(ar + ks * 32 + g * 8);
  }

  floatx4 acc[2][10];
#pragma unroll
  for (int rs = 0; rs < 2; rs++)
#pragma unroll
    for (int j = 0; j < 10; j++) acc[rs][j] = (floatx4){0.f, 0.f, 0.f, 0.f};

#pragma unroll
  for (int p = 0; p < 8; ++p) {
    const int cb = p & 1;
    __syncthreads();
    if (p < 7) stage(p + 1, cb ^ 1);
#pragma unroll
    for (int ksub = 0; ksub < 2; ++ksub)
#pragma unroll
      for (int j = 0; j < 10; ++j) {
        short8 b = sB[cb][(ksub * 20 + nh * 10 + j) * 64 + lane];
#pragma unroll
        for (int rs = 0; rs < 2; rs++)
          acc[rs][j] = __builtin_amdgcn_mfma_f32_16x16x32_bf16(
              af[rs][p * 2 + ksub], b, acc[rs][j], 0, 0, 0);
      }
  }

#pragma unroll
  for (int rs = 0; rs < 2; rs++)
#pragma unroll
    for (int j = 0; j < 10; ++j) {
      int col = nh * 160 + j * 16 + lr;
      float bb = bo[col];
#pragma unroll
      for (int reg = 0; reg < 4; reg++) {
        int row = row0 + rs * 16 + g * 4 + reg;
        out[(size_t)row * 320 + col] = acc[rs][j][reg] + bb;
      }
    }
}

// ---------------------------------------------------------------- launch ----
extern "C" void kernel_launch(void* const* d_in, const int* in_sizes, int n_in,
                              void* d_out, int out_size, void* d_ws, size_t ws_size,
                              hipStream_t stream) {
  (void)in_sizes; (void)n_in; (void)out_size; (void)ws_size;
  const float* x    = (const float*)d_in[0];
  const float* Wq   = (const float*)d_in[1];
  const float* Wk   = (const float*)d_in[2];
  const float* Wv   = (const float*)d_in[3];
  const float* Wo   = (const float*)d_in[4];
  const float* bo   = (const float*)d_in[5];
  const float* relk = (const float*)d_in[6];
  const float* relv = (const float*)d_in[7];
  float* out = (float*)d_out;

  unsigned short* wqkvT   = (unsigned short*)d_ws;              // 983040 B
  unsigned short* woT     = wqkvT + NWQKV;                      // 327680 B
  unsigned short* attnout = woT + NWO;                          // 134217728 B

  prep_kernel<<<(NWQKV + NWO) / 256, 256, 0, stream>>>(Wq, Wk, Wv, Wo, wqkvT, woT);
  qkv_attn_kernel<<<683, 256, 0, stream>>>(x, relk, relv, wqkvT, attnout);
  out_proj_kernel<<<1024, 512, 0, stream>>>(attnout, woT, bo, out);
}